// Round 16
// baseline (266.755 us; speedup 1.0000x reference)
//
#include <hip/hip_runtime.h>
#include <hip/hip_bf16.h>

#define NV 50000
#define ND 300
#define NDP 320      // K of layer-1 padded to multiple of 32
#define NG 256
#define NE 1600000
#define NBS 4096     // B*S
#define NBUCK 196    // ceil(50000/256) buckets of 256 nodes (dst>>8)
#define EPB 4096     // edges per block in scatter
#define SCAT_BLOCKS 391  // ceil(NE/EPB)
#define CPAD 16      // bucket counter pad: 16 ints = 64 B line per counter
#define GEMM1_BLOCKS 782   // ceil(50000/128) * (256/128)
// prep2 block ranges: scatter | W1 split | W2 split | emb->bf16
#define P2_W1 320          // NG*NDP/256
#define P2_W2 256          // NG*NG/256
#define P2_EMB 7813        // ceil(NV*40/256)
#define HIST_BLOCKS 1024

typedef short short8 __attribute__((ext_vector_type(8)));
typedef float f32x4 __attribute__((ext_vector_type(4)));
typedef float f32x2 __attribute__((ext_vector_type(2)));
typedef _Float16 half4 __attribute__((ext_vector_type(4)));

__device__ __forceinline__ ushort f2bf(float f) {
    unsigned u = __builtin_bit_cast(unsigned, f);
    unsigned r = (u + 0x7fffu + ((u >> 16) & 1u)) >> 16;
    return (ushort)r;
}
__device__ __forceinline__ float bf2f(ushort h) {
    unsigned u = ((unsigned)h) << 16;
    return __builtin_bit_cast(float, u);
}

// ------- bucket histogram (LDS-aggregated, padded global counters) -------
__global__ __launch_bounds__(256) void hist_kernel(const int* __restrict__ dst,
                                                   int* __restrict__ bucket_count) {
    __shared__ int bh[NBUCK];
    int t = threadIdx.x;
    for (int b = t; b < NBUCK; b += 256) bh[b] = 0;
    __syncthreads();
    for (int i = blockIdx.x * 256 + t; i * 4 < NE; i += HIST_BLOCKS * 256) {
        int4 d = *(const int4*)(dst + i * 4);
        atomicAdd(&bh[d.x >> 8], 1);
        atomicAdd(&bh[d.y >> 8], 1);
        atomicAdd(&bh[d.z >> 8], 1);
        atomicAdd(&bh[d.w >> 8], 1);
    }
    __syncthreads();
    for (int b = t; b < NBUCK; b += 256)
        if (bh[b]) atomicAdd(&bucket_count[b * CPAD], bh[b]);
}

// ------- bucket scan: one block, Hillis-Steele over 196 padded counts -------
__global__ __launch_bounds__(256) void bucket_scan(const int* __restrict__ bucket_count,
                                                   int* __restrict__ bucket_base,
                                                   int* __restrict__ bucket_cursor) {
    __shared__ int s[256];
    int t = threadIdx.x;
    int v = (t < NBUCK) ? bucket_count[t * CPAD] : 0;
    s[t] = v;
    __syncthreads();
    for (int d = 1; d < 256; d <<= 1) {
        int x = (t >= d) ? s[t - d] : 0;
        __syncthreads();
        s[t] += x;
        __syncthreads();
    }
    int excl = s[t] - v;
    if (t < NBUCK) {
        bucket_base[t] = excl;
        bucket_cursor[t * CPAD] = excl;
    }
    if (t == 255) bucket_base[NBUCK] = s[255];  // = NE
}

// ===== PREP2 (fused): scatter [0,391) ∥ W1 split ∥ W2 split ∥ emb->bf16 =====
__global__ __launch_bounds__(256) void prep2_kernel(const int* __restrict__ ei,
                                                    int* __restrict__ bucket_cursor,
                                                    unsigned* __restrict__ rec,
                                                    const float* __restrict__ W1,
                                                    const float* __restrict__ W2,
                                                    ushort* __restrict__ W1Th,
                                                    ushort* __restrict__ W2Th,
                                                    ushort* __restrict__ W2Tl,
                                                    const float* __restrict__ emb,
                                                    ushort* __restrict__ embB) {
    int t = threadIdx.x;
    if (blockIdx.x < SCAT_BLOCKS) {
        __shared__ int cnt[NBUCK];
        __shared__ int basel[NBUCK];
        int e0 = blockIdx.x * EPB;
        for (int b = t; b < NBUCK; b += 256) cnt[b] = 0;
        __syncthreads();
        for (int q = 0; q < EPB / 1024; ++q) {
            int i4 = e0 + q * 1024 + t * 4;
            if (i4 < NE) {
                int4 d = *(const int4*)(ei + NE + i4);
                atomicAdd(&cnt[d.x >> 8], 1);
                atomicAdd(&cnt[d.y >> 8], 1);
                atomicAdd(&cnt[d.z >> 8], 1);
                atomicAdd(&cnt[d.w >> 8], 1);
            }
        }
        __syncthreads();
        for (int b = t; b < NBUCK; b += 256) {
            int c = cnt[b];
            basel[b] = c ? atomicAdd(&bucket_cursor[b * CPAD], c) : 0;
        }
        __syncthreads();
        for (int b = t; b < NBUCK; b += 256) cnt[b] = 0;
        __syncthreads();
        for (int q = 0; q < EPB / 1024; ++q) {
            int i4 = e0 + q * 1024 + t * 4;
            if (i4 < NE) {
                int4 s = *(const int4*)(ei + i4);
                int4 d = *(const int4*)(ei + NE + i4);
                int b0 = d.x >> 8, b1 = d.y >> 8, b2 = d.z >> 8, b3 = d.w >> 8;
                int r0 = atomicAdd(&cnt[b0], 1);
                rec[basel[b0] + r0] = (unsigned)s.x | ((unsigned)(d.x & 255) << 16);
                int r1 = atomicAdd(&cnt[b1], 1);
                rec[basel[b1] + r1] = (unsigned)s.y | ((unsigned)(d.y & 255) << 16);
                int r2 = atomicAdd(&cnt[b2], 1);
                rec[basel[b2] + r2] = (unsigned)s.z | ((unsigned)(d.z & 255) << 16);
                int r3 = atomicAdd(&cnt[b3], 1);
                rec[basel[b3] + r3] = (unsigned)s.w | ((unsigned)(d.w & 255) << 16);
            }
        }
    } else if (blockIdx.x < SCAT_BLOCKS + P2_W1) {
        int idx = (blockIdx.x - SCAT_BLOCKS) * 256 + t;   // < NG*NDP
        int n = idx / NDP, k = idx - n * NDP;
        float v = (k < ND) ? W1[(size_t)k * NG + n] : 0.f;
        W1Th[idx] = f2bf(v);
    } else if (blockIdx.x < SCAT_BLOCKS + P2_W1 + P2_W2) {
        int j = (blockIdx.x - SCAT_BLOCKS - P2_W1) * 256 + t;  // < NG*NG
        int n = j / NG, k = j - n * NG;
        float v = W2[(size_t)k * NG + n];
        ushort h = f2bf(v);
        W2Th[j] = h;
        W2Tl[j] = f2bf(v - bf2f(h));
    } else {
        int u = (blockIdx.x - SCAT_BLOCKS - P2_W1 - P2_W2) * 256 + t;
        if (u < NV * 40) {
            int row = u / 40;
            int kq = (u - row * 40) * 8;
            short8 o;
            if (kq + 8 <= ND) {
                float4 p0 = *(const float4*)(emb + (size_t)row * ND + kq);
                float4 p1 = *(const float4*)(emb + (size_t)row * ND + kq + 4);
                o[0] = (short)f2bf(p0.x); o[1] = (short)f2bf(p0.y);
                o[2] = (short)f2bf(p0.z); o[3] = (short)f2bf(p0.w);
                o[4] = (short)f2bf(p1.x); o[5] = (short)f2bf(p1.y);
                o[6] = (short)f2bf(p1.z); o[7] = (short)f2bf(p1.w);
            } else {
#pragma unroll
                for (int e = 0; e < 8; ++e) {
                    int k = kq + e;
                    float v = (k < ND) ? emb[(size_t)row * ND + k] : 0.f;
                    o[e] = (short)f2bf(v);
                }
            }
            *(short8*)(embB + (size_t)row * NDP + kq) = o;
        }
    }
}

// ===== FUSED: csr_build [0,196) ∥ gemm1 (h1 = embB@W1 -> fp8 QUARTERED) [196,978) =====
// h1q layout: [quarter q = col>>6][node][64 bytes], each quarter = 3.2 MB (L2-resident).
__global__ __launch_bounds__(256) void csr_gemm1(const unsigned* __restrict__ rec,
                                                 const int* __restrict__ bucket_base,
                                                 int* __restrict__ off,
                                                 float* __restrict__ inv_sqrt,
                                                 ushort* __restrict__ csr_src,
                                                 const ushort* __restrict__ embB,
                                                 const ushort* __restrict__ BTh,
                                                 unsigned char* __restrict__ h1q) {
    int t = threadIdx.x;
    if (blockIdx.x < NBUCK) {
        __shared__ int degl[256];
        __shared__ int s[256];
        int b = blockIdx.x;
        degl[t] = 0;
        __syncthreads();
        int r0 = bucket_base[b], r1 = bucket_base[b + 1];
        for (int i = r0 + t; i < r1; i += 256)
            atomicAdd(&degl[(rec[i] >> 16) & 255], 1);
        __syncthreads();
        int v = degl[t];
        s[t] = v;
        __syncthreads();
        for (int d = 1; d < 256; d <<= 1) {
            int x = (t >= d) ? s[t - d] : 0;
            __syncthreads();
            s[t] += x;
            __syncthreads();
        }
        int excl = s[t] - v + r0;
        int n = (b << 8) + t;
        if (n < NV) {
            off[n] = excl;
            inv_sqrt[n] = rsqrtf((float)(v + 1));  // deg = 1 (self loop) + in-degree
        }
        if (b == NBUCK - 1 && t == 0) off[NV] = NE;
        __syncthreads();
        degl[t] = excl;  // reuse as cursor
        __syncthreads();
        for (int i = r0 + t; i < r1; i += 256) {
            unsigned e = rec[i];
            int p = atomicAdd(&degl[(e >> 16) & 255], 1);
            csr_src[p] = (ushort)(e & 0xffff);
        }
    } else {
        __shared__ short Ah[128][40];
        __shared__ short Bh[128][40];
        const int M = NV, KP = NDP;
        int bid = blockIdx.x - NBUCK;
        int bm = (bid >> 1) * 128;
        int bn = (bid & 1) * 128;
        int lane = t & 63, wv = t >> 6;
        int wm = (wv >> 1) * 64, wn = (wv & 1) * 64;
        int srow = t >> 1;
        int skq = (t & 1) * 16;
        f32x4 acc[4][4];
#pragma unroll
        for (int mi = 0; mi < 4; ++mi)
#pragma unroll
            for (int ni = 0; ni < 4; ++ni) acc[mi][ni] = (f32x4)0.0f;

        for (int k0 = 0; k0 < KP; k0 += 32) {
            int gk = k0 + skq;
            {
                int gr = bm + srow;
                short8 va0, va1;
                if (gr < M) {
                    va0 = *(const short8*)(embB + (size_t)gr * NDP + gk);
                    va1 = *(const short8*)(embB + (size_t)gr * NDP + gk + 8);
                } else {
                    va0 = (short8)0;
                    va1 = (short8)0;
                }
                *(short8*)&Ah[srow][skq] = va0;
                *(short8*)&Ah[srow][skq + 8] = va1;
            }
            {
                int nr = bn + srow;
                short8 bh0 = *(const short8*)(BTh + (size_t)nr * NDP + gk);
                short8 bh1 = *(const short8*)(BTh + (size_t)nr * NDP + gk + 8);
                *(short8*)&Bh[srow][skq] = bh0;
                *(short8*)&Bh[srow][skq + 8] = bh1;
            }
            __syncthreads();
            int m16 = lane & 15, kb = (lane >> 4) * 8;
            short8 a_h[4], b_h[4];
#pragma unroll
            for (int mi = 0; mi < 4; ++mi)
                a_h[mi] = *(const short8*)&Ah[wm + mi * 16 + m16][kb];
#pragma unroll
            for (int ni = 0; ni < 4; ++ni)
                b_h[ni] = *(const short8*)&Bh[wn + ni * 16 + m16][kb];
#pragma unroll
            for (int mi = 0; mi < 4; ++mi)
#pragma unroll
                for (int ni = 0; ni < 4; ++ni)
                    acc[mi][ni] = __builtin_amdgcn_mfma_f32_16x16x32_bf16(a_h[mi], b_h[ni], acc[mi][ni], 0, 0, 0);
            __syncthreads();
        }
        int m16 = lane & 15, rq = lane >> 4;
#pragma unroll
        for (int mi = 0; mi < 4; ++mi)
#pragma unroll
            for (int ni = 0; ni < 4; ++ni) {
                int row0 = bm + wm + mi * 16 + rq * 4;
                int col = bn + wn + ni * 16 + m16;
                size_t base = (size_t)(col >> 6) * NV * 64 + (col & 63);
                int p01 = __builtin_amdgcn_cvt_pk_fp8_f32(acc[mi][ni][0], acc[mi][ni][1], 0, false);
                int p23 = __builtin_amdgcn_cvt_pk_fp8_f32(acc[mi][ni][2], acc[mi][ni][3], 0, false);
                if (row0 + 0 < M) h1q[base + (size_t)(row0 + 0) * 64] = (unsigned char)(p01 & 0xff);
                if (row0 + 1 < M) h1q[base + (size_t)(row0 + 1) * 64] = (unsigned char)((p01 >> 8) & 0xff);
                if (row0 + 2 < M) h1q[base + (size_t)(row0 + 2) * 64] = (unsigned char)(p23 & 0xff);
                if (row0 + 3 < M) h1q[base + (size_t)(row0 + 3) * 64] = (unsigned char)((p23 >> 8) & 0xff);
            }
    }
}

// ---- standalone MFMA GEMM (out = y @ W2 + b2), 2-pass split for accuracy ----
__global__ __launch_bounds__(256) void gemm_out(const float* __restrict__ A,
                                                int lda,
                                                const ushort* __restrict__ BTh,
                                                const ushort* __restrict__ BTl,
                                                int ldb,
                                                int M, int K, int KP,
                                                float* __restrict__ C32,
                                                const float* __restrict__ bias) {
    __shared__ short Ah[128][40];
    __shared__ short Bh[128][40];
    __shared__ short Bl[128][40];
    int t = threadIdx.x;
    int bm = blockIdx.x * 128;
    int bn = blockIdx.y * 128;
    int lane = t & 63, wv = t >> 6;
    int wm = (wv >> 1) * 64, wn = (wv & 1) * 64;
    int srow = t >> 1;
    int skq = (t & 1) * 16;
    f32x4 acc[4][4];
#pragma unroll
    for (int mi = 0; mi < 4; ++mi)
#pragma unroll
        for (int ni = 0; ni < 4; ++ni) acc[mi][ni] = (f32x4)0.0f;

    for (int k0 = 0; k0 < KP; k0 += 32) {
        int gk = k0 + skq;
        {
            int gr = bm + srow;
            short va[16];
            float v[16];
            if (gr < M && gk < K) {
#pragma unroll
                for (int q = 0; q < 4; ++q) {
                    float4 p = *(const float4*)(A + (size_t)gr * lda + gk + q * 4);
                    v[q * 4 + 0] = p.x; v[q * 4 + 1] = p.y;
                    v[q * 4 + 2] = p.z; v[q * 4 + 3] = p.w;
                }
            } else {
#pragma unroll
                for (int e = 0; e < 16; ++e) v[e] = 0.f;
            }
#pragma unroll
            for (int e = 0; e < 16; ++e) va[e] = (short)f2bf(v[e]);
            *(short8*)&Ah[srow][skq] = *(short8*)&va[0];
            *(short8*)&Ah[srow][skq + 8] = *(short8*)&va[8];
        }
        {
            int nr = bn + srow;
            short8 bh0 = *(const short8*)(BTh + (size_t)nr * ldb + gk);
            short8 bh1 = *(const short8*)(BTh + (size_t)nr * ldb + gk + 8);
            short8 bl0 = *(const short8*)(BTl + (size_t)nr * ldb + gk);
            short8 bl1 = *(const short8*)(BTl + (size_t)nr * ldb + gk + 8);
            *(short8*)&Bh[srow][skq] = bh0;
            *(short8*)&Bh[srow][skq + 8] = bh1;
            *(short8*)&Bl[srow][skq] = bl0;
            *(short8*)&Bl[srow][skq + 8] = bl1;
        }
        __syncthreads();
        int m16 = lane & 15, kb = (lane >> 4) * 8;
        short8 a_h[4], b_h[4], b_l[4];
#pragma unroll
        for (int mi = 0; mi < 4; ++mi)
            a_h[mi] = *(const short8*)&Ah[wm + mi * 16 + m16][kb];
#pragma unroll
        for (int ni = 0; ni < 4; ++ni) {
            b_h[ni] = *(const short8*)&Bh[wn + ni * 16 + m16][kb];
            b_l[ni] = *(const short8*)&Bl[wn + ni * 16 + m16][kb];
        }
#pragma unroll
        for (int mi = 0; mi < 4; ++mi)
#pragma unroll
            for (int ni = 0; ni < 4; ++ni) {
                acc[mi][ni] = __builtin_amdgcn_mfma_f32_16x16x32_bf16(a_h[mi], b_h[ni], acc[mi][ni], 0, 0, 0);
                acc[mi][ni] = __builtin_amdgcn_mfma_f32_16x16x32_bf16(a_h[mi], b_l[ni], acc[mi][ni], 0, 0, 0);
            }
        __syncthreads();
    }
    int m16 = lane & 15, rq = lane >> 4;
#pragma unroll
    for (int mi = 0; mi < 4; ++mi)
#pragma unroll
        for (int ni = 0; ni < 4; ++ni) {
#pragma unroll
            for (int r = 0; r < 4; ++r) {
                int row = bm + wm + mi * 16 + rq * 4 + r;
                int col = bn + wn + ni * 16 + m16;
                if (row < M)
                    C32[(size_t)row * NG + col] = acc[mi][ni][r] + bias[col];
            }
        }
}

// ---- layer-1 agg, channel-quartered: blockIdx.y = quarter (3.2 MB table, L2-resident).
// Wave per node; 16-lane group g handles one edge (64 B = 1 cache line), 4 edges/instr.
__global__ __launch_bounds__(256) void agg1_kernel(const unsigned char* __restrict__ h1q,
                                                   const int* __restrict__ off,
                                                   const ushort* __restrict__ csr_src,
                                                   const float* __restrict__ inv_sqrt,
                                                   const float* __restrict__ b1,
                                                   _Float16* __restrict__ x1) {
    int wv = threadIdx.x >> 6, lane = threadIdx.x & 63;
    int i = blockIdx.x * 4 + wv;
    if (i >= NV) return;
    int q = blockIdx.y;
    int g = lane >> 4, p = lane & 15;        // g: edge sub-slot, p: dword within 64 B
    const unsigned char* hb = h1q + (size_t)q * NV * 64;
    int s0 = off[i], s1 = off[i + 1];
    float a0 = 0.f, a1 = 0.f, a2 = 0.f, a3 = 0.f;
    int j = s0;
    for (; j + 32 <= s1; j += 32) {          // 8 independent chains per lane
        int sx[8];
        float wx[8];
        unsigned pk[8];
#pragma unroll
        for (int u = 0; u < 8; ++u) sx[u] = csr_src[j + u * 4 + g];
#pragma unroll
        for (int u = 0; u < 8; ++u) {
            wx[u] = inv_sqrt[sx[u]];
            pk[u] = *(const unsigned*)(hb + (size_t)sx[u] * 64 + p * 4);
        }
#pragma unroll
        for (int u = 0; u < 8; ++u) {
            f32x2 v01 = __builtin_amdgcn_cvt_pk_f32_fp8(pk[u], false);
            f32x2 v23 = __builtin_amdgcn_cvt_pk_f32_fp8(pk[u], true);
            a0 += wx[u] * v01[0];
            a1 += wx[u] * v01[1];
            a2 += wx[u] * v23[0];
            a3 += wx[u] * v23[1];
        }
    }
    for (; j < s1; j += 4) {                 // tail: 4 edges per step, mask invalid
        int idx = j + g;
        bool vld = idx < s1;
        int sx = csr_src[vld ? idx : s0];
        float w = vld ? inv_sqrt[sx] : 0.f;
        unsigned pk = *(const unsigned*)(hb + (size_t)sx * 64 + p * 4);
        f32x2 v01 = __builtin_amdgcn_cvt_pk_f32_fp8(pk, false);
        f32x2 v23 = __builtin_amdgcn_cvt_pk_f32_fp8(pk, true);
        a0 += w * v01[0];
        a1 += w * v01[1];
        a2 += w * v23[0];
        a3 += w * v23[1];
    }
    // reduce the 4 edge groups
    a0 += __shfl_xor(a0, 16, 64);
    a1 += __shfl_xor(a1, 16, 64);
    a2 += __shfl_xor(a2, 16, 64);
    a3 += __shfl_xor(a3, 16, 64);
    a0 += __shfl_xor(a0, 32, 64);
    a1 += __shfl_xor(a1, 32, 64);
    a2 += __shfl_xor(a2, 32, 64);
    a3 += __shfl_xor(a3, 32, 64);
    if (g == 0) {
        float is = inv_sqrt[i], is2 = is * is;
        unsigned pks = *(const unsigned*)(hb + (size_t)i * 64 + p * 4);
        f32x2 s01 = __builtin_amdgcn_cvt_pk_f32_fp8(pks, false);
        f32x2 s23 = __builtin_amdgcn_cvt_pk_f32_fp8(pks, true);
        float4 bb = *(const float4*)(b1 + q * 64 + p * 4);
        half4 o;
        o[0] = (_Float16)fmaxf(is * a0 + s01[0] * is2 + bb.x, 0.f);
        o[1] = (_Float16)fmaxf(is * a1 + s01[1] * is2 + bb.y, 0.f);
        o[2] = (_Float16)fmaxf(is * a2 + s23[0] * is2 + bb.z, 0.f);
        o[3] = (_Float16)fmaxf(is * a3 + s23[1] * is2 + bb.w, 0.f);
        *(half4*)(x1 + (size_t)i * NG + q * 64 + p * 4) = o;
    }
}

// ---- layer-2 agg on x1 at word positions only (W2 deferred), unroll-16 ----
__global__ __launch_bounds__(256) void agg2_kernel(const _Float16* __restrict__ x1,
                                                   const int* __restrict__ off,
                                                   const ushort* __restrict__ csr_src,
                                                   const float* __restrict__ inv_sqrt,
                                                   const int* __restrict__ word_ids,
                                                   float* __restrict__ y) {
    int wv = threadIdx.x >> 6, lane = threadIdx.x & 63;
    int p = blockIdx.x * 4 + wv;
    if (p >= NBS) return;
    int n = word_ids[p];
    int c4 = lane * 4;
    int s0 = off[n], s1 = off[n + 1];
    float a0 = 0.f, a1 = 0.f, a2 = 0.f, a3 = 0.f;
    int j = s0;
    for (; j + 16 <= s1; j += 16) {
        int sx[16];
        float wx[16];
        half4 vx[16];
#pragma unroll
        for (int u = 0; u < 16; ++u) sx[u] = csr_src[j + u];
#pragma unroll
        for (int u = 0; u < 16; ++u) {
            wx[u] = inv_sqrt[sx[u]];
            vx[u] = *(const half4*)(x1 + (size_t)sx[u] * NG + c4);
        }
#pragma unroll
        for (int u = 0; u < 16; ++u) {
            a0 += wx[u] * (float)vx[u][0];
            a1 += wx[u] * (float)vx[u][1];
            a2 += wx[u] * (float)vx[u][2];
            a3 += wx[u] * (float)vx[u][3];
        }
    }
    for (; j + 4 <= s1; j += 4) {
        int sx[4];
        float wx[4];
        half4 vx[4];
#pragma unroll
        for (int u = 0; u < 4; ++u) sx[u] = csr_src[j + u];
#pragma unroll
        for (int u = 0; u < 4; ++u) {
            wx[u] = inv_sqrt[sx[u]];
            vx[u] = *(const half4*)(x1 + (size_t)sx[u] * NG + c4);
        }
#pragma unroll
        for (int u = 0; u < 4; ++u) {
            a0 += wx[u] * (float)vx[u][0];
            a1 += wx[u] * (float)vx[u][1];
            a2 += wx[u] * (float)vx[u][2];
            a3 += wx[u] * (float)vx[u][3];
        }
    }
    for (; j < s1; ++j) {
        int s = csr_src[j];
        float w = inv_sqrt[s];
        half4 hv = *(const half4*)(x1 + (size_t)s * NG + c4);
        a0 += w * (float)hv[0];
        a1 += w * (float)hv[1];
        a2 += w * (float)hv[2];
        a3 += w * (float)hv[3];
    }
    float is = inv_sqrt[n], is2 = is * is;
    half4 sv = *(const half4*)(x1 + (size_t)n * NG + c4);
    float4 o;
    o.x = is * a0 + (float)sv[0] * is2;
    o.y = is * a1 + (float)sv[1] * is2;
    o.z = is * a2 + (float)sv[2] * is2;
    o.w = is * a3 + (float)sv[3] * is2;
    *(float4*)(y + (size_t)p * NG + c4) = o;
}

extern "C" void kernel_launch(void* const* d_in, const int* in_sizes, int n_in,
                              void* d_out, int out_size, void* d_ws, size_t ws_size,
                              hipStream_t stream) {
    const float* emb = (const float*)d_in[0];       // V x D
    const float* W1  = (const float*)d_in[1];       // D x G
    const float* b1  = (const float*)d_in[2];       // G
    const float* W2  = (const float*)d_in[3];       // G x G
    const float* b2  = (const float*)d_in[4];       // G
    const int*   ei  = (const int*)d_in[5];         // 2 x E
    const int*   wid = (const int*)d_in[6];         // B x S
    float* out = (float*)d_out;

    char* w = (char*)d_ws;
    auto alloc = [&](size_t bytes) {
        void* p = (void*)w;
        w += (bytes + 255) & ~(size_t)255;
        return p;
    };
    int*    off      = (int*)alloc((size_t)(NV + 1) * 4);
    float*  inv_sqrt = (float*)alloc((size_t)NV * 4);
    int*    bucket_count  = (int*)alloc((size_t)NBUCK * CPAD * 4);
    int*    bucket_base   = (int*)alloc((size_t)(NBUCK + 1) * 4);
    int*    bucket_cursor = (int*)alloc((size_t)NBUCK * CPAD * 4);
    ushort* csr_src  = (ushort*)alloc((size_t)NE * 2);
    unsigned* bucket_rec = (unsigned*)alloc((size_t)NE * 4);
    ushort* W1T_h    = (ushort*)alloc((size_t)NG * NDP * 2);
    ushort* W2T_h    = (ushort*)alloc((size_t)NG * NG * 2);
    ushort* W2T_l    = (ushort*)alloc((size_t)NG * NG * 2);
    ushort* embB     = (ushort*)alloc((size_t)NV * NDP * 2);   // bf16 emb, zero-padded
    unsigned char* h1q = (unsigned char*)alloc((size_t)NV * NG);  // quartered [4][NV][64]
    _Float16* x1     = (_Float16*)alloc((size_t)NV * NG * 2);
    float*  y        = (float*)alloc((size_t)NBS * NG * 4);

    hipMemsetAsync(bucket_count, 0, (size_t)NBUCK * CPAD * 4, stream);

    // hist (gates only bucket_scan)
    hist_kernel<<<HIST_BLOCKS, 256, 0, stream>>>(ei + NE, bucket_count);
    bucket_scan<<<1, 256, 0, stream>>>(bucket_count, bucket_base, bucket_cursor);
    // prep2: scatter ∥ W1 split ∥ W2 split ∥ emb->bf16 (all independent)
    prep2_kernel<<<SCAT_BLOCKS + P2_W1 + P2_W2 + P2_EMB, 256, 0, stream>>>(
        ei, bucket_cursor, bucket_rec, W1, W2, W1T_h, W2T_h, W2T_l, emb, embB);
    // fused: csr_build ∥ gemm1 (h1 = embB@W1 -> fp8 quartered)
    csr_gemm1<<<NBUCK + GEMM1_BLOCKS, 256, 0, stream>>>(bucket_rec, bucket_base,
                                                        off, inv_sqrt, csr_src,
                                                        embB, W1T_h, h1q);
    // x1 = relu(norm-agg(h1) + b1): 4 channel-quarter passes, each table L2-resident
    {
        dim3 grid((NV + 3) / 4, 4);
        agg1_kernel<<<grid, 256, 0, stream>>>(h1q, off, csr_src, inv_sqrt, b1, x1);
    }
    // y = norm-agg(x1) at word positions (fp32)
    agg2_kernel<<<(NBS + 3) / 4, 256, 0, stream>>>(x1, off, csr_src, inv_sqrt, wid, y);
    // out = y @ W2 + b2  (fp32)
    {
        dim3 grid((NBS + 127) / 128, NG / 128);
        gemm_out<<<grid, 256, 0, stream>>>(y, NG, W2T_h, W2T_l, NG,
                                           NBS, NG, NG, out, b2);
    }
}

// Round 17
// 165.023 us; speedup vs baseline: 1.6165x; 1.6165x over previous
//
#include <hip/hip_runtime.h>
#include <hip/hip_bf16.h>

#define NV 50000
#define ND 300
#define NDP 320      // K of layer-1 padded to multiple of 32
#define NG 256
#define NE 1600000
#define NBS 4096     // B*S
#define NBUCK 196    // ceil(50000/256) buckets of 256 nodes (dst>>8)
#define BCAP 9216    // fixed bucket capacity: mean 8163 + ~11.6 sigma
#define EPB 4096     // edges per block in scatter
#define SCAT_BLOCKS 391  // ceil(NE/EPB)
#define CPAD 16      // bucket counter pad: 16 ints = 64 B line per counter
#define GEMM1_BLOCKS 782   // ceil(50000/128) * (256/128)
// prep2 block ranges: scatter | W1 split | W2 split | emb->bf16
#define P2_W1 320          // NG*NDP/256
#define P2_W2 256          // NG*NG/256
#define P2_EMB 7813        // ceil(NV*40/256)

typedef short short8 __attribute__((ext_vector_type(8)));
typedef float f32x4 __attribute__((ext_vector_type(4)));
typedef float f32x2 __attribute__((ext_vector_type(2)));
typedef _Float16 half4 __attribute__((ext_vector_type(4)));

__device__ __forceinline__ ushort f2bf(float f) {
    unsigned u = __builtin_bit_cast(unsigned, f);
    unsigned r = (u + 0x7fffu + ((u >> 16) & 1u)) >> 16;
    return (ushort)r;
}
__device__ __forceinline__ float bf2f(ushort h) {
    unsigned u = ((unsigned)h) << 16;
    return __builtin_bit_cast(float, u);
}

// ===== PREP2 (fused, first kernel): scatter (fixed-cap buckets) ∥ W1 ∥ W2 ∥ emb->bf16 =====
__global__ __launch_bounds__(256) void prep2_kernel(const int* __restrict__ ei,
                                                    int* __restrict__ bucket_cursor,
                                                    unsigned* __restrict__ rec,
                                                    const float* __restrict__ W1,
                                                    const float* __restrict__ W2,
                                                    ushort* __restrict__ W1Th,
                                                    ushort* __restrict__ W2Th,
                                                    ushort* __restrict__ W2Tl,
                                                    const float* __restrict__ emb,
                                                    ushort* __restrict__ embB) {
    int t = threadIdx.x;
    if (blockIdx.x < SCAT_BLOCKS) {
        // ---------- scatter: edges -> fixed-capacity dst-buckets, 4 B packed records ----------
        __shared__ int cnt[NBUCK];
        __shared__ int basel[NBUCK];
        int e0 = blockIdx.x * EPB;
        for (int b = t; b < NBUCK; b += 256) cnt[b] = 0;
        __syncthreads();
        for (int q = 0; q < EPB / 1024; ++q) {
            int i4 = e0 + q * 1024 + t * 4;
            if (i4 < NE) {
                int4 d = *(const int4*)(ei + NE + i4);
                atomicAdd(&cnt[d.x >> 8], 1);
                atomicAdd(&cnt[d.y >> 8], 1);
                atomicAdd(&cnt[d.z >> 8], 1);
                atomicAdd(&cnt[d.w >> 8], 1);
            }
        }
        __syncthreads();
        for (int b = t; b < NBUCK; b += 256) {
            int c = cnt[b];
            basel[b] = c ? atomicAdd(&bucket_cursor[b * CPAD], c) : 0;
        }
        __syncthreads();
        for (int b = t; b < NBUCK; b += 256) cnt[b] = 0;
        __syncthreads();
        for (int q = 0; q < EPB / 1024; ++q) {
            int i4 = e0 + q * 1024 + t * 4;
            if (i4 < NE) {
                int4 s = *(const int4*)(ei + i4);
                int4 d = *(const int4*)(ei + NE + i4);
                int b0 = d.x >> 8, b1 = d.y >> 8, b2 = d.z >> 8, b3 = d.w >> 8;
                int r0 = atomicAdd(&cnt[b0], 1);
                rec[(size_t)b0 * BCAP + basel[b0] + r0] = (unsigned)s.x | ((unsigned)(d.x & 255) << 16);
                int r1 = atomicAdd(&cnt[b1], 1);
                rec[(size_t)b1 * BCAP + basel[b1] + r1] = (unsigned)s.y | ((unsigned)(d.y & 255) << 16);
                int r2 = atomicAdd(&cnt[b2], 1);
                rec[(size_t)b2 * BCAP + basel[b2] + r2] = (unsigned)s.z | ((unsigned)(d.z & 255) << 16);
                int r3 = atomicAdd(&cnt[b3], 1);
                rec[(size_t)b3 * BCAP + basel[b3] + r3] = (unsigned)s.w | ((unsigned)(d.w & 255) << 16);
            }
        }
    } else if (blockIdx.x < SCAT_BLOCKS + P2_W1) {
        // ---------- W1 transpose, hi only (gemm1 is single-pass) ----------
        int idx = (blockIdx.x - SCAT_BLOCKS) * 256 + t;   // < NG*NDP
        int n = idx / NDP, k = idx - n * NDP;
        float v = (k < ND) ? W1[(size_t)k * NG + n] : 0.f;
        W1Th[idx] = f2bf(v);
    } else if (blockIdx.x < SCAT_BLOCKS + P2_W1 + P2_W2) {
        // ---------- W2 transpose + hi/lo split (gemm_out is 2-pass) ----------
        int j = (blockIdx.x - SCAT_BLOCKS - P2_W1) * 256 + t;  // < NG*NG
        int n = j / NG, k = j - n * NG;
        float v = W2[(size_t)k * NG + n];
        ushort h = f2bf(v);
        W2Th[j] = h;
        W2Tl[j] = f2bf(v - bf2f(h));
    } else {
        // ---------- emb fp32 [NV][300] -> bf16 [NV][320] zero-padded ----------
        int u = (blockIdx.x - SCAT_BLOCKS - P2_W1 - P2_W2) * 256 + t;
        if (u < NV * 40) {
            int row = u / 40;
            int kq = (u - row * 40) * 8;
            short8 o;
            if (kq + 8 <= ND) {
                float4 p0 = *(const float4*)(emb + (size_t)row * ND + kq);
                float4 p1 = *(const float4*)(emb + (size_t)row * ND + kq + 4);
                o[0] = (short)f2bf(p0.x); o[1] = (short)f2bf(p0.y);
                o[2] = (short)f2bf(p0.z); o[3] = (short)f2bf(p0.w);
                o[4] = (short)f2bf(p1.x); o[5] = (short)f2bf(p1.y);
                o[6] = (short)f2bf(p1.z); o[7] = (short)f2bf(p1.w);
            } else {
#pragma unroll
                for (int e = 0; e < 8; ++e) {
                    int k = kq + e;
                    float v = (k < ND) ? emb[(size_t)row * ND + k] : 0.f;
                    o[e] = (short)f2bf(v);
                }
            }
            *(short8*)(embB + (size_t)row * NDP + kq) = o;
        }
    }
}

// ------- bucket scan (after scatter): counts -> global exclusive prefix -------
__global__ __launch_bounds__(256) void bucket_scan(const int* __restrict__ bucket_cursor,
                                                   int* __restrict__ bucket_base) {
    __shared__ int s[256];
    int t = threadIdx.x;
    int v = (t < NBUCK) ? bucket_cursor[t * CPAD] : 0;
    s[t] = v;
    __syncthreads();
    for (int d = 1; d < 256; d <<= 1) {
        int x = (t >= d) ? s[t - d] : 0;
        __syncthreads();
        s[t] += x;
        __syncthreads();
    }
    int excl = s[t] - v;
    if (t < NBUCK) bucket_base[t] = excl;
    if (t == 255) bucket_base[NBUCK] = s[255];  // = NE
}

// ===== FUSED: csr_build [0,196) ∥ gemm1 (h1 = embB@W1 -> fp8) [196,978) =====
__global__ __launch_bounds__(256) void csr_gemm1(const unsigned* __restrict__ rec,
                                                 const int* __restrict__ bucket_base,
                                                 int* __restrict__ off,
                                                 float* __restrict__ inv_sqrt,
                                                 ushort* __restrict__ csr_src,
                                                 const ushort* __restrict__ embB,
                                                 const ushort* __restrict__ BTh,
                                                 unsigned char* __restrict__ C8) {
    int t = threadIdx.x;
    if (blockIdx.x < NBUCK) {
        // ---------- csr_build: per bucket LDS degree count + scan + place ----------
        __shared__ int degl[256];
        __shared__ int s[256];
        int b = blockIdx.x;
        degl[t] = 0;
        __syncthreads();
        int r0 = bucket_base[b];
        int cntb = bucket_base[b + 1] - r0;
        const unsigned* rb = rec + (size_t)b * BCAP;
        for (int i = t; i < cntb; i += 256)
            atomicAdd(&degl[(rb[i] >> 16) & 255], 1);
        __syncthreads();
        int v = degl[t];
        s[t] = v;
        __syncthreads();
        for (int d = 1; d < 256; d <<= 1) {
            int x = (t >= d) ? s[t - d] : 0;
            __syncthreads();
            s[t] += x;
            __syncthreads();
        }
        int excl = s[t] - v + r0;
        int n = (b << 8) + t;
        if (n < NV) {
            off[n] = excl;
            inv_sqrt[n] = rsqrtf((float)(v + 1));  // deg = 1 (self loop) + in-degree
        }
        if (b == NBUCK - 1 && t == 0) off[NV] = NE;
        __syncthreads();
        degl[t] = excl;  // reuse as cursor
        __syncthreads();
        for (int i = t; i < cntb; i += 256) {
            unsigned e = rb[i];
            int p = atomicAdd(&degl[(e >> 16) & 255], 1);
            csr_src[p] = (ushort)(e & 0xffff);
        }
    } else {
        // ---------- GEMM: 128x128 tile, bf16 A (prestaged) x B_h, fp8 out ----------
        __shared__ short Ah[128][40];
        __shared__ short Bh[128][40];
        const int M = NV, KP = NDP;
        int bid = blockIdx.x - NBUCK;
        int bm = (bid >> 1) * 128;
        int bn = (bid & 1) * 128;
        int lane = t & 63, wv = t >> 6;
        int wm = (wv >> 1) * 64, wn = (wv & 1) * 64;
        int srow = t >> 1;
        int skq = (t & 1) * 16;
        f32x4 acc[4][4];
#pragma unroll
        for (int mi = 0; mi < 4; ++mi)
#pragma unroll
            for (int ni = 0; ni < 4; ++ni) acc[mi][ni] = (f32x4)0.0f;

        for (int k0 = 0; k0 < KP; k0 += 32) {
            int gk = k0 + skq;
            {
                int gr = bm + srow;
                short8 va0, va1;
                if (gr < M) {
                    va0 = *(const short8*)(embB + (size_t)gr * NDP + gk);
                    va1 = *(const short8*)(embB + (size_t)gr * NDP + gk + 8);
                } else {
                    va0 = (short8)0;
                    va1 = (short8)0;
                }
                *(short8*)&Ah[srow][skq] = va0;
                *(short8*)&Ah[srow][skq + 8] = va1;
            }
            {
                int nr = bn + srow;
                short8 bh0 = *(const short8*)(BTh + (size_t)nr * NDP + gk);
                short8 bh1 = *(const short8*)(BTh + (size_t)nr * NDP + gk + 8);
                *(short8*)&Bh[srow][skq] = bh0;
                *(short8*)&Bh[srow][skq + 8] = bh1;
            }
            __syncthreads();
            int m16 = lane & 15, kb = (lane >> 4) * 8;
            short8 a_h[4], b_h[4];
#pragma unroll
            for (int mi = 0; mi < 4; ++mi)
                a_h[mi] = *(const short8*)&Ah[wm + mi * 16 + m16][kb];
#pragma unroll
            for (int ni = 0; ni < 4; ++ni)
                b_h[ni] = *(const short8*)&Bh[wn + ni * 16 + m16][kb];
#pragma unroll
            for (int mi = 0; mi < 4; ++mi)
#pragma unroll
                for (int ni = 0; ni < 4; ++ni)
                    acc[mi][ni] = __builtin_amdgcn_mfma_f32_16x16x32_bf16(a_h[mi], b_h[ni], acc[mi][ni], 0, 0, 0);
            __syncthreads();
        }
        int m16 = lane & 15, rq = lane >> 4;
#pragma unroll
        for (int mi = 0; mi < 4; ++mi)
#pragma unroll
            for (int ni = 0; ni < 4; ++ni) {
                int row0 = bm + wm + mi * 16 + rq * 4;
                int col = bn + wn + ni * 16 + m16;
                int p01 = __builtin_amdgcn_cvt_pk_fp8_f32(acc[mi][ni][0], acc[mi][ni][1], 0, false);
                int p23 = __builtin_amdgcn_cvt_pk_fp8_f32(acc[mi][ni][2], acc[mi][ni][3], 0, false);
                if (row0 + 0 < M) C8[(size_t)(row0 + 0) * NG + col] = (unsigned char)(p01 & 0xff);
                if (row0 + 1 < M) C8[(size_t)(row0 + 1) * NG + col] = (unsigned char)((p01 >> 8) & 0xff);
                if (row0 + 2 < M) C8[(size_t)(row0 + 2) * NG + col] = (unsigned char)(p23 & 0xff);
                if (row0 + 3 < M) C8[(size_t)(row0 + 3) * NG + col] = (unsigned char)((p23 >> 8) & 0xff);
            }
    }
}

// ---- standalone MFMA GEMM (out = y @ W2 + b2), 2-pass split for accuracy ----
__global__ __launch_bounds__(256) void gemm_out(const float* __restrict__ A,
                                                int lda,
                                                const ushort* __restrict__ BTh,
                                                const ushort* __restrict__ BTl,
                                                int ldb,
                                                int M, int K, int KP,
                                                float* __restrict__ C32,
                                                const float* __restrict__ bias) {
    __shared__ short Ah[128][40];
    __shared__ short Bh[128][40];
    __shared__ short Bl[128][40];
    int t = threadIdx.x;
    int bm = blockIdx.x * 128;
    int bn = blockIdx.y * 128;
    int lane = t & 63, wv = t >> 6;
    int wm = (wv >> 1) * 64, wn = (wv & 1) * 64;
    int srow = t >> 1;
    int skq = (t & 1) * 16;
    f32x4 acc[4][4];
#pragma unroll
    for (int mi = 0; mi < 4; ++mi)
#pragma unroll
        for (int ni = 0; ni < 4; ++ni) acc[mi][ni] = (f32x4)0.0f;

    for (int k0 = 0; k0 < KP; k0 += 32) {
        int gk = k0 + skq;
        {
            int gr = bm + srow;
            short va[16];
            float v[16];
            if (gr < M && gk < K) {
#pragma unroll
                for (int q = 0; q < 4; ++q) {
                    float4 p = *(const float4*)(A + (size_t)gr * lda + gk + q * 4);
                    v[q * 4 + 0] = p.x; v[q * 4 + 1] = p.y;
                    v[q * 4 + 2] = p.z; v[q * 4 + 3] = p.w;
                }
            } else {
#pragma unroll
                for (int e = 0; e < 16; ++e) v[e] = 0.f;
            }
#pragma unroll
            for (int e = 0; e < 16; ++e) va[e] = (short)f2bf(v[e]);
            *(short8*)&Ah[srow][skq] = *(short8*)&va[0];
            *(short8*)&Ah[srow][skq + 8] = *(short8*)&va[8];
        }
        {
            int nr = bn + srow;
            short8 bh0 = *(const short8*)(BTh + (size_t)nr * ldb + gk);
            short8 bh1 = *(const short8*)(BTh + (size_t)nr * ldb + gk + 8);
            short8 bl0 = *(const short8*)(BTl + (size_t)nr * ldb + gk);
            short8 bl1 = *(const short8*)(BTl + (size_t)nr * ldb + gk + 8);
            *(short8*)&Bh[srow][skq] = bh0;
            *(short8*)&Bh[srow][skq + 8] = bh1;
            *(short8*)&Bl[srow][skq] = bl0;
            *(short8*)&Bl[srow][skq + 8] = bl1;
        }
        __syncthreads();
        int m16 = lane & 15, kb = (lane >> 4) * 8;
        short8 a_h[4], b_h[4], b_l[4];
#pragma unroll
        for (int mi = 0; mi < 4; ++mi)
            a_h[mi] = *(const short8*)&Ah[wm + mi * 16 + m16][kb];
#pragma unroll
        for (int ni = 0; ni < 4; ++ni) {
            b_h[ni] = *(const short8*)&Bh[wn + ni * 16 + m16][kb];
            b_l[ni] = *(const short8*)&Bl[wn + ni * 16 + m16][kb];
        }
#pragma unroll
        for (int mi = 0; mi < 4; ++mi)
#pragma unroll
            for (int ni = 0; ni < 4; ++ni) {
                acc[mi][ni] = __builtin_amdgcn_mfma_f32_16x16x32_bf16(a_h[mi], b_h[ni], acc[mi][ni], 0, 0, 0);
                acc[mi][ni] = __builtin_amdgcn_mfma_f32_16x16x32_bf16(a_h[mi], b_l[ni], acc[mi][ni], 0, 0, 0);
            }
        __syncthreads();
    }
    int m16 = lane & 15, rq = lane >> 4;
#pragma unroll
    for (int mi = 0; mi < 4; ++mi)
#pragma unroll
        for (int ni = 0; ni < 4; ++ni) {
#pragma unroll
            for (int r = 0; r < 4; ++r) {
                int row = bm + wm + mi * 16 + rq * 4 + r;
                int col = bn + wn + ni * 16 + m16;
                if (row < M)
                    C32[(size_t)row * NG + col] = acc[mi][ni][r] + bias[col];
            }
        }
}

// ---- layer-1 agg: wave per node, unroll-16 fp8 gather (HW cvt), row-major h1 ----
__global__ __launch_bounds__(256) void agg1_kernel(const unsigned char* __restrict__ h1f8,
                                                   const int* __restrict__ off,
                                                   const ushort* __restrict__ csr_src,
                                                   const float* __restrict__ inv_sqrt,
                                                   const float* __restrict__ b1,
                                                   _Float16* __restrict__ x1) {
    int wv = threadIdx.x >> 6, lane = threadIdx.x & 63;
    int i = blockIdx.x * 4 + wv;
    if (i >= NV) return;
    int c4 = lane * 4;
    int s0 = off[i], s1 = off[i + 1];
    float a0 = 0.f, a1 = 0.f, a2 = 0.f, a3 = 0.f;
    int j = s0;
    for (; j + 16 <= s1; j += 16) {
        int sx[16];
        float wx[16];
        unsigned pk[16];
#pragma unroll
        for (int u = 0; u < 16; ++u) sx[u] = csr_src[j + u];
#pragma unroll
        for (int u = 0; u < 16; ++u) {
            wx[u] = inv_sqrt[sx[u]];
            pk[u] = *(const unsigned*)(h1f8 + (size_t)sx[u] * NG + c4);
        }
#pragma unroll
        for (int u = 0; u < 16; ++u) {
            f32x2 v01 = __builtin_amdgcn_cvt_pk_f32_fp8(pk[u], false);
            f32x2 v23 = __builtin_amdgcn_cvt_pk_f32_fp8(pk[u], true);
            a0 += wx[u] * v01[0];
            a1 += wx[u] * v01[1];
            a2 += wx[u] * v23[0];
            a3 += wx[u] * v23[1];
        }
    }
    for (; j + 4 <= s1; j += 4) {
        int sx[4];
        float wx[4];
        unsigned pk[4];
#pragma unroll
        for (int u = 0; u < 4; ++u) sx[u] = csr_src[j + u];
#pragma unroll
        for (int u = 0; u < 4; ++u) {
            wx[u] = inv_sqrt[sx[u]];
            pk[u] = *(const unsigned*)(h1f8 + (size_t)sx[u] * NG + c4);
        }
#pragma unroll
        for (int u = 0; u < 4; ++u) {
            f32x2 v01 = __builtin_amdgcn_cvt_pk_f32_fp8(pk[u], false);
            f32x2 v23 = __builtin_amdgcn_cvt_pk_f32_fp8(pk[u], true);
            a0 += wx[u] * v01[0];
            a1 += wx[u] * v01[1];
            a2 += wx[u] * v23[0];
            a3 += wx[u] * v23[1];
        }
    }
    for (; j < s1; ++j) {
        int s = csr_src[j];
        float w = inv_sqrt[s];
        unsigned pk = *(const unsigned*)(h1f8 + (size_t)s * NG + c4);
        f32x2 v01 = __builtin_amdgcn_cvt_pk_f32_fp8(pk, false);
        f32x2 v23 = __builtin_amdgcn_cvt_pk_f32_fp8(pk, true);
        a0 += w * v01[0];
        a1 += w * v01[1];
        a2 += w * v23[0];
        a3 += w * v23[1];
    }
    float is = inv_sqrt[i], is2 = is * is;
    unsigned pks = *(const unsigned*)(h1f8 + (size_t)i * NG + c4);
    f32x2 s01 = __builtin_amdgcn_cvt_pk_f32_fp8(pks, false);
    f32x2 s23 = __builtin_amdgcn_cvt_pk_f32_fp8(pks, true);
    float4 bb = *(const float4*)(b1 + c4);
    half4 o;
    o[0] = (_Float16)fmaxf(is * a0 + s01[0] * is2 + bb.x, 0.f);
    o[1] = (_Float16)fmaxf(is * a1 + s01[1] * is2 + bb.y, 0.f);
    o[2] = (_Float16)fmaxf(is * a2 + s23[0] * is2 + bb.z, 0.f);
    o[3] = (_Float16)fmaxf(is * a3 + s23[1] * is2 + bb.w, 0.f);
    *(half4*)(x1 + (size_t)i * NG + c4) = o;
}

// ---- layer-2 agg on x1 at word positions only (W2 deferred), unroll-16 ----
__global__ __launch_bounds__(256) void agg2_kernel(const _Float16* __restrict__ x1,
                                                   const int* __restrict__ off,
                                                   const ushort* __restrict__ csr_src,
                                                   const float* __restrict__ inv_sqrt,
                                                   const int* __restrict__ word_ids,
                                                   float* __restrict__ y) {
    int wv = threadIdx.x >> 6, lane = threadIdx.x & 63;
    int p = blockIdx.x * 4 + wv;
    if (p >= NBS) return;
    int n = word_ids[p];
    int c4 = lane * 4;
    int s0 = off[n], s1 = off[n + 1];
    float a0 = 0.f, a1 = 0.f, a2 = 0.f, a3 = 0.f;
    int j = s0;
    for (; j + 16 <= s1; j += 16) {
        int sx[16];
        float wx[16];
        half4 vx[16];
#pragma unroll
        for (int u = 0; u < 16; ++u) sx[u] = csr_src[j + u];
#pragma unroll
        for (int u = 0; u < 16; ++u) {
            wx[u] = inv_sqrt[sx[u]];
            vx[u] = *(const half4*)(x1 + (size_t)sx[u] * NG + c4);
        }
#pragma unroll
        for (int u = 0; u < 16; ++u) {
            a0 += wx[u] * (float)vx[u][0];
            a1 += wx[u] * (float)vx[u][1];
            a2 += wx[u] * (float)vx[u][2];
            a3 += wx[u] * (float)vx[u][3];
        }
    }
    for (; j + 4 <= s1; j += 4) {
        int sx[4];
        float wx[4];
        half4 vx[4];
#pragma unroll
        for (int u = 0; u < 4; ++u) sx[u] = csr_src[j + u];
#pragma unroll
        for (int u = 0; u < 4; ++u) {
            wx[u] = inv_sqrt[sx[u]];
            vx[u] = *(const half4*)(x1 + (size_t)sx[u] * NG + c4);
        }
#pragma unroll
        for (int u = 0; u < 4; ++u) {
            a0 += wx[u] * (float)vx[u][0];
            a1 += wx[u] * (float)vx[u][1];
            a2 += wx[u] * (float)vx[u][2];
            a3 += wx[u] * (float)vx[u][3];
        }
    }
    for (; j < s1; ++j) {
        int s = csr_src[j];
        float w = inv_sqrt[s];
        half4 hv = *(const half4*)(x1 + (size_t)s * NG + c4);
        a0 += w * (float)hv[0];
        a1 += w * (float)hv[1];
        a2 += w * (float)hv[2];
        a3 += w * (float)hv[3];
    }
    float is = inv_sqrt[n], is2 = is * is;
    half4 sv = *(const half4*)(x1 + (size_t)n * NG + c4);
    float4 o;
    o.x = is * a0 + (float)sv[0] * is2;
    o.y = is * a1 + (float)sv[1] * is2;
    o.z = is * a2 + (float)sv[2] * is2;
    o.w = is * a3 + (float)sv[3] * is2;
    *(float4*)(y + (size_t)p * NG + c4) = o;
}

extern "C" void kernel_launch(void* const* d_in, const int* in_sizes, int n_in,
                              void* d_out, int out_size, void* d_ws, size_t ws_size,
                              hipStream_t stream) {
    const float* emb = (const float*)d_in[0];       // V x D
    const float* W1  = (const float*)d_in[1];       // D x G
    const float* b1  = (const float*)d_in[2];       // G
    const float* W2  = (const float*)d_in[3];       // G x G
    const float* b2  = (const float*)d_in[4];       // G
    const int*   ei  = (const int*)d_in[5];         // 2 x E
    const int*   wid = (const int*)d_in[6];         // B x S
    float* out = (float*)d_out;

    char* w = (char*)d_ws;
    auto alloc = [&](size_t bytes) {
        void* p = (void*)w;
        w += (bytes + 255) & ~(size_t)255;
        return p;
    };
    int*    off      = (int*)alloc((size_t)(NV + 1) * 4);
    float*  inv_sqrt = (float*)alloc((size_t)NV * 4);
    int*    bucket_base   = (int*)alloc((size_t)(NBUCK + 1) * 4);
    int*    bucket_cursor = (int*)alloc((size_t)NBUCK * CPAD * 4);
    ushort* csr_src  = (ushort*)alloc((size_t)NE * 2);
    unsigned* bucket_rec = (unsigned*)alloc((size_t)NBUCK * BCAP * 4);
    ushort* W1T_h    = (ushort*)alloc((size_t)NG * NDP * 2);
    ushort* W2T_h    = (ushort*)alloc((size_t)NG * NG * 2);
    ushort* W2T_l    = (ushort*)alloc((size_t)NG * NG * 2);
    ushort* embB     = (ushort*)alloc((size_t)NV * NDP * 2);   // bf16 emb, zero-padded
    unsigned char* h1f8 = (unsigned char*)alloc((size_t)NV * NG);
    _Float16* x1     = (_Float16*)alloc((size_t)NV * NG * 2);
    float*  y        = (float*)alloc((size_t)NBS * NG * 4);

    hipMemsetAsync(bucket_cursor, 0, (size_t)NBUCK * CPAD * 4, stream);

    // prep2 (first real kernel, no upstream dep): scatter ∥ W1 ∥ W2 ∥ emb->bf16
    prep2_kernel<<<SCAT_BLOCKS + P2_W1 + P2_W2 + P2_EMB, 256, 0, stream>>>(
        ei, bucket_cursor, bucket_rec, W1, W2, W1T_h, W2T_h, W2T_l, emb, embB);
    // bucket scan on observed counts -> global CSR base offsets
    bucket_scan<<<1, 256, 0, stream>>>(bucket_cursor, bucket_base);
    // fused: csr_build ∥ gemm1 (h1 = embB@W1 -> fp8)
    csr_gemm1<<<NBUCK + GEMM1_BLOCKS, 256, 0, stream>>>(bucket_rec, bucket_base,
                                                        off, inv_sqrt, csr_src,
                                                        embB, W1T_h, h1f8);
    // x1 = relu(norm-agg(h1) + b1)  (fp16 out)
    agg1_kernel<<<(NV + 3) / 4, 256, 0, stream>>>(h1f8, off, csr_src, inv_sqrt, b1, x1);
    // y = norm-agg(x1) at word positions (fp32)
    agg2_kernel<<<(NBS + 3) / 4, 256, 0, stream>>>(x1, off, csr_src, inv_sqrt, wid, y);
    // out = y @ W2 + b2  (fp32)
    {
        dim3 grid((NBS + 127) / 128, NG / 128);
        gemm_out<<<grid, 256, 0, stream>>>(y, NG, W2T_h, W2T_l, NG,
                                           NBS, NG, NG, out, b2);
    }
}

// Round 18
// 159.306 us; speedup vs baseline: 1.6745x; 1.0359x over previous
//
#include <hip/hip_runtime.h>
#include <hip/hip_bf16.h>

#define NV 50000
#define ND 300
#define NDP 320      // K of layer-1 padded to multiple of 32
#define NG 256
#define NE 1600000
#define NBS 4096     // B*S
#define NBUCK 196    // ceil(50000/256) buckets of 256 nodes (dst>>8)
#define BCAP 9216    // fixed bucket capacity: mean 8192 + ~11.3 sigma
#define EPB 4096     // edges per block in scatter
#define SCAT_BLOCKS 391  // ceil(NE/EPB)
#define CPAD 16      // bucket counter pad: 16 ints = 64 B line per counter
#define GEMM1_BLOCKS 782   // ceil(50000/128) * (256/128)
// prep2 block ranges: scatter | W1 split | W2 split | emb->bf16
#define P2_W1 320          // NG*NDP/256
#define P2_W2 256          // NG*NG/256
#define P2_EMB 7813        // ceil(NV*40/256)

typedef short short8 __attribute__((ext_vector_type(8)));
typedef float f32x4 __attribute__((ext_vector_type(4)));
typedef float f32x2 __attribute__((ext_vector_type(2)));
typedef _Float16 half4 __attribute__((ext_vector_type(4)));

__device__ __forceinline__ ushort f2bf(float f) {
    unsigned u = __builtin_bit_cast(unsigned, f);
    unsigned r = (u + 0x7fffu + ((u >> 16) & 1u)) >> 16;
    return (ushort)r;
}
__device__ __forceinline__ float bf2f(ushort h) {
    unsigned u = ((unsigned)h) << 16;
    return __builtin_bit_cast(float, u);
}

// ===== PREP2 (fused, first kernel): scatter (fixed-cap buckets) ∥ W1 ∥ W2 ∥ emb->bf16 =====
__global__ __launch_bounds__(256) void prep2_kernel(const int* __restrict__ ei,
                                                    int* __restrict__ bucket_cursor,
                                                    unsigned* __restrict__ rec,
                                                    const float* __restrict__ W1,
                                                    const float* __restrict__ W2,
                                                    ushort* __restrict__ W1Th,
                                                    ushort* __restrict__ W2Th,
                                                    ushort* __restrict__ W2Tl,
                                                    const float* __restrict__ emb,
                                                    ushort* __restrict__ embB) {
    int t = threadIdx.x;
    if (blockIdx.x < SCAT_BLOCKS) {
        // ---------- scatter: edges -> fixed-capacity dst-buckets, 4 B packed records ----------
        __shared__ int cnt[NBUCK];
        __shared__ int basel[NBUCK];
        int e0 = blockIdx.x * EPB;
        for (int b = t; b < NBUCK; b += 256) cnt[b] = 0;
        __syncthreads();
        for (int q = 0; q < EPB / 1024; ++q) {
            int i4 = e0 + q * 1024 + t * 4;
            if (i4 < NE) {
                int4 d = *(const int4*)(ei + NE + i4);
                atomicAdd(&cnt[d.x >> 8], 1);
                atomicAdd(&cnt[d.y >> 8], 1);
                atomicAdd(&cnt[d.z >> 8], 1);
                atomicAdd(&cnt[d.w >> 8], 1);
            }
        }
        __syncthreads();
        for (int b = t; b < NBUCK; b += 256) {
            int c = cnt[b];
            basel[b] = c ? atomicAdd(&bucket_cursor[b * CPAD], c) : 0;
        }
        __syncthreads();
        for (int b = t; b < NBUCK; b += 256) cnt[b] = 0;
        __syncthreads();
        for (int q = 0; q < EPB / 1024; ++q) {
            int i4 = e0 + q * 1024 + t * 4;
            if (i4 < NE) {
                int4 s = *(const int4*)(ei + i4);
                int4 d = *(const int4*)(ei + NE + i4);
                int b0 = d.x >> 8, b1 = d.y >> 8, b2 = d.z >> 8, b3 = d.w >> 8;
                int r0 = atomicAdd(&cnt[b0], 1);
                rec[(size_t)b0 * BCAP + basel[b0] + r0] = (unsigned)s.x | ((unsigned)(d.x & 255) << 16);
                int r1 = atomicAdd(&cnt[b1], 1);
                rec[(size_t)b1 * BCAP + basel[b1] + r1] = (unsigned)s.y | ((unsigned)(d.y & 255) << 16);
                int r2 = atomicAdd(&cnt[b2], 1);
                rec[(size_t)b2 * BCAP + basel[b2] + r2] = (unsigned)s.z | ((unsigned)(d.z & 255) << 16);
                int r3 = atomicAdd(&cnt[b3], 1);
                rec[(size_t)b3 * BCAP + basel[b3] + r3] = (unsigned)s.w | ((unsigned)(d.w & 255) << 16);
            }
        }
    } else if (blockIdx.x < SCAT_BLOCKS + P2_W1) {
        // ---------- W1 transpose, hi only (gemm1 is single-pass) ----------
        int idx = (blockIdx.x - SCAT_BLOCKS) * 256 + t;   // < NG*NDP
        int n = idx / NDP, k = idx - n * NDP;
        float v = (k < ND) ? W1[(size_t)k * NG + n] : 0.f;
        W1Th[idx] = f2bf(v);
    } else if (blockIdx.x < SCAT_BLOCKS + P2_W1 + P2_W2) {
        // ---------- W2 transpose + hi/lo split (gemm_out is 2-pass) ----------
        int j = (blockIdx.x - SCAT_BLOCKS - P2_W1) * 256 + t;  // < NG*NG
        int n = j / NG, k = j - n * NG;
        float v = W2[(size_t)k * NG + n];
        ushort h = f2bf(v);
        W2Th[j] = h;
        W2Tl[j] = f2bf(v - bf2f(h));
    } else {
        // ---------- emb fp32 [NV][300] -> bf16 [NV][320] zero-padded ----------
        int u = (blockIdx.x - SCAT_BLOCKS - P2_W1 - P2_W2) * 256 + t;
        if (u < NV * 40) {
            int row = u / 40;
            int kq = (u - row * 40) * 8;
            short8 o;
            if (kq + 8 <= ND) {
                float4 p0 = *(const float4*)(emb + (size_t)row * ND + kq);
                float4 p1 = *(const float4*)(emb + (size_t)row * ND + kq + 4);
                o[0] = (short)f2bf(p0.x); o[1] = (short)f2bf(p0.y);
                o[2] = (short)f2bf(p0.z); o[3] = (short)f2bf(p0.w);
                o[4] = (short)f2bf(p1.x); o[5] = (short)f2bf(p1.y);
                o[6] = (short)f2bf(p1.z); o[7] = (short)f2bf(p1.w);
            } else {
#pragma unroll
                for (int e = 0; e < 8; ++e) {
                    int k = kq + e;
                    float v = (k < ND) ? emb[(size_t)row * ND + k] : 0.f;
                    o[e] = (short)f2bf(v);
                }
            }
            *(short8*)(embB + (size_t)row * NDP + kq) = o;
        }
    }
}

// ===== FUSED: csr_build [0,196) ∥ gemm1 (h1 = embB@W1 -> fp8) [196,978) =====
// CSR uses FIXED per-bucket bases (b*BCAP): no global scan needed.
// Per-node range is [off[n], end[n]).
__global__ __launch_bounds__(256) void csr_gemm1(const unsigned* __restrict__ rec,
                                                 const int* __restrict__ bucket_cnt,
                                                 int* __restrict__ off,
                                                 int* __restrict__ endv,
                                                 float* __restrict__ inv_sqrt,
                                                 ushort* __restrict__ csr_src,
                                                 const ushort* __restrict__ embB,
                                                 const ushort* __restrict__ BTh,
                                                 unsigned char* __restrict__ C8) {
    int t = threadIdx.x;
    if (blockIdx.x < NBUCK) {
        // ---------- csr_build: per bucket LDS degree count + scan + place ----------
        __shared__ int degl[256];
        __shared__ int s[256];
        int b = blockIdx.x;
        degl[t] = 0;
        __syncthreads();
        int r0 = b * BCAP;                       // fixed base in csr arrays
        int cntb = bucket_cnt[b * CPAD];
        const unsigned* rb = rec + (size_t)b * BCAP;
        for (int i = t; i < cntb; i += 256)
            atomicAdd(&degl[(rb[i] >> 16) & 255], 1);
        __syncthreads();
        int v = degl[t];
        s[t] = v;
        __syncthreads();
        for (int d = 1; d < 256; d <<= 1) {
            int x = (t >= d) ? s[t - d] : 0;
            __syncthreads();
            s[t] += x;
            __syncthreads();
        }
        int excl = s[t] - v + r0;
        int n = (b << 8) + t;
        if (n < NV) {
            off[n] = excl;
            endv[n] = excl + v;
            inv_sqrt[n] = rsqrtf((float)(v + 1));  // deg = 1 (self loop) + in-degree
        }
        __syncthreads();
        degl[t] = excl;  // reuse as cursor
        __syncthreads();
        for (int i = t; i < cntb; i += 256) {
            unsigned e = rb[i];
            int p = atomicAdd(&degl[(e >> 16) & 255], 1);
            csr_src[p] = (ushort)(e & 0xffff);
        }
    } else {
        // ---------- GEMM: 128x128 tile, bf16 A (prestaged) x B_h, fp8 out ----------
        __shared__ short Ah[128][40];
        __shared__ short Bh[128][40];
        const int M = NV, KP = NDP;
        int bid = blockIdx.x - NBUCK;
        int bm = (bid >> 1) * 128;
        int bn = (bid & 1) * 128;
        int lane = t & 63, wv = t >> 6;
        int wm = (wv >> 1) * 64, wn = (wv & 1) * 64;
        int srow = t >> 1;
        int skq = (t & 1) * 16;
        f32x4 acc[4][4];
#pragma unroll
        for (int mi = 0; mi < 4; ++mi)
#pragma unroll
            for (int ni = 0; ni < 4; ++ni) acc[mi][ni] = (f32x4)0.0f;

        for (int k0 = 0; k0 < KP; k0 += 32) {
            int gk = k0 + skq;
            {
                int gr = bm + srow;
                short8 va0, va1;
                if (gr < M) {
                    va0 = *(const short8*)(embB + (size_t)gr * NDP + gk);
                    va1 = *(const short8*)(embB + (size_t)gr * NDP + gk + 8);
                } else {
                    va0 = (short8)0;
                    va1 = (short8)0;
                }
                *(short8*)&Ah[srow][skq] = va0;
                *(short8*)&Ah[srow][skq + 8] = va1;
            }
            {
                int nr = bn + srow;
                short8 bh0 = *(const short8*)(BTh + (size_t)nr * NDP + gk);
                short8 bh1 = *(const short8*)(BTh + (size_t)nr * NDP + gk + 8);
                *(short8*)&Bh[srow][skq] = bh0;
                *(short8*)&Bh[srow][skq + 8] = bh1;
            }
            __syncthreads();
            int m16 = lane & 15, kb = (lane >> 4) * 8;
            short8 a_h[4], b_h[4];
#pragma unroll
            for (int mi = 0; mi < 4; ++mi)
                a_h[mi] = *(const short8*)&Ah[wm + mi * 16 + m16][kb];
#pragma unroll
            for (int ni = 0; ni < 4; ++ni)
                b_h[ni] = *(const short8*)&Bh[wn + ni * 16 + m16][kb];
#pragma unroll
            for (int mi = 0; mi < 4; ++mi)
#pragma unroll
                for (int ni = 0; ni < 4; ++ni)
                    acc[mi][ni] = __builtin_amdgcn_mfma_f32_16x16x32_bf16(a_h[mi], b_h[ni], acc[mi][ni], 0, 0, 0);
            __syncthreads();
        }
        int m16 = lane & 15, rq = lane >> 4;
#pragma unroll
        for (int mi = 0; mi < 4; ++mi)
#pragma unroll
            for (int ni = 0; ni < 4; ++ni) {
                int row0 = bm + wm + mi * 16 + rq * 4;
                int col = bn + wn + ni * 16 + m16;
                int p01 = __builtin_amdgcn_cvt_pk_fp8_f32(acc[mi][ni][0], acc[mi][ni][1], 0, false);
                int p23 = __builtin_amdgcn_cvt_pk_fp8_f32(acc[mi][ni][2], acc[mi][ni][3], 0, false);
                if (row0 + 0 < M) C8[(size_t)(row0 + 0) * NG + col] = (unsigned char)(p01 & 0xff);
                if (row0 + 1 < M) C8[(size_t)(row0 + 1) * NG + col] = (unsigned char)((p01 >> 8) & 0xff);
                if (row0 + 2 < M) C8[(size_t)(row0 + 2) * NG + col] = (unsigned char)(p23 & 0xff);
                if (row0 + 3 < M) C8[(size_t)(row0 + 3) * NG + col] = (unsigned char)((p23 >> 8) & 0xff);
            }
    }
}

// ---- standalone MFMA GEMM (out = y @ W2 + b2), 2-pass split for accuracy ----
__global__ __launch_bounds__(256) void gemm_out(const float* __restrict__ A,
                                                int lda,
                                                const ushort* __restrict__ BTh,
                                                const ushort* __restrict__ BTl,
                                                int ldb,
                                                int M, int K, int KP,
                                                float* __restrict__ C32,
                                                const float* __restrict__ bias) {
    __shared__ short Ah[128][40];
    __shared__ short Bh[128][40];
    __shared__ short Bl[128][40];
    int t = threadIdx.x;
    int bm = blockIdx.x * 128;
    int bn = blockIdx.y * 128;
    int lane = t & 63, wv = t >> 6;
    int wm = (wv >> 1) * 64, wn = (wv & 1) * 64;
    int srow = t >> 1;
    int skq = (t & 1) * 16;
    f32x4 acc[4][4];
#pragma unroll
    for (int mi = 0; mi < 4; ++mi)
#pragma unroll
        for (int ni = 0; ni < 4; ++ni) acc[mi][ni] = (f32x4)0.0f;

    for (int k0 = 0; k0 < KP; k0 += 32) {
        int gk = k0 + skq;
        {
            int gr = bm + srow;
            short va[16];
            float v[16];
            if (gr < M && gk < K) {
#pragma unroll
                for (int q = 0; q < 4; ++q) {
                    float4 p = *(const float4*)(A + (size_t)gr * lda + gk + q * 4);
                    v[q * 4 + 0] = p.x; v[q * 4 + 1] = p.y;
                    v[q * 4 + 2] = p.z; v[q * 4 + 3] = p.w;
                }
            } else {
#pragma unroll
                for (int e = 0; e < 16; ++e) v[e] = 0.f;
            }
#pragma unroll
            for (int e = 0; e < 16; ++e) va[e] = (short)f2bf(v[e]);
            *(short8*)&Ah[srow][skq] = *(short8*)&va[0];
            *(short8*)&Ah[srow][skq + 8] = *(short8*)&va[8];
        }
        {
            int nr = bn + srow;
            short8 bh0 = *(const short8*)(BTh + (size_t)nr * ldb + gk);
            short8 bh1 = *(const short8*)(BTh + (size_t)nr * ldb + gk + 8);
            short8 bl0 = *(const short8*)(BTl + (size_t)nr * ldb + gk);
            short8 bl1 = *(const short8*)(BTl + (size_t)nr * ldb + gk + 8);
            *(short8*)&Bh[srow][skq] = bh0;
            *(short8*)&Bh[srow][skq + 8] = bh1;
            *(short8*)&Bl[srow][skq] = bl0;
            *(short8*)&Bl[srow][skq + 8] = bl1;
        }
        __syncthreads();
        int m16 = lane & 15, kb = (lane >> 4) * 8;
        short8 a_h[4], b_h[4], b_l[4];
#pragma unroll
        for (int mi = 0; mi < 4; ++mi)
            a_h[mi] = *(const short8*)&Ah[wm + mi * 16 + m16][kb];
#pragma unroll
        for (int ni = 0; ni < 4; ++ni) {
            b_h[ni] = *(const short8*)&Bh[wn + ni * 16 + m16][kb];
            b_l[ni] = *(const short8*)&Bl[wn + ni * 16 + m16][kb];
        }
#pragma unroll
        for (int mi = 0; mi < 4; ++mi)
#pragma unroll
            for (int ni = 0; ni < 4; ++ni) {
                acc[mi][ni] = __builtin_amdgcn_mfma_f32_16x16x32_bf16(a_h[mi], b_h[ni], acc[mi][ni], 0, 0, 0);
                acc[mi][ni] = __builtin_amdgcn_mfma_f32_16x16x32_bf16(a_h[mi], b_l[ni], acc[mi][ni], 0, 0, 0);
            }
        __syncthreads();
    }
    int m16 = lane & 15, rq = lane >> 4;
#pragma unroll
    for (int mi = 0; mi < 4; ++mi)
#pragma unroll
        for (int ni = 0; ni < 4; ++ni) {
#pragma unroll
            for (int r = 0; r < 4; ++r) {
                int row = bm + wm + mi * 16 + rq * 4 + r;
                int col = bn + wn + ni * 16 + m16;
                if (row < M)
                    C32[(size_t)row * NG + col] = acc[mi][ni][r] + bias[col];
            }
        }
}

// ---- layer-1 agg: wave per node, unroll-16 fp8 gather (HW cvt), row-major h1 ----
__global__ __launch_bounds__(256) void agg1_kernel(const unsigned char* __restrict__ h1f8,
                                                   const int* __restrict__ off,
                                                   const int* __restrict__ endv,
                                                   const ushort* __restrict__ csr_src,
                                                   const float* __restrict__ inv_sqrt,
                                                   const float* __restrict__ b1,
                                                   _Float16* __restrict__ x1) {
    int wv = threadIdx.x >> 6, lane = threadIdx.x & 63;
    int i = blockIdx.x * 4 + wv;
    if (i >= NV) return;
    int c4 = lane * 4;
    int s0 = off[i], s1 = endv[i];
    float a0 = 0.f, a1 = 0.f, a2 = 0.f, a3 = 0.f;
    int j = s0;
    for (; j + 16 <= s1; j += 16) {
        int sx[16];
        float wx[16];
        unsigned pk[16];
#pragma unroll
        for (int u = 0; u < 16; ++u) sx[u] = csr_src[j + u];
#pragma unroll
        for (int u = 0; u < 16; ++u) {
            wx[u] = inv_sqrt[sx[u]];
            pk[u] = *(const unsigned*)(h1f8 + (size_t)sx[u] * NG + c4);
        }
#pragma unroll
        for (int u = 0; u < 16; ++u) {
            f32x2 v01 = __builtin_amdgcn_cvt_pk_f32_fp8(pk[u], false);
            f32x2 v23 = __builtin_amdgcn_cvt_pk_f32_fp8(pk[u], true);
            a0 += wx[u] * v01[0];
            a1 += wx[u] * v01[1];
            a2 += wx[u] * v23[0];
            a3 += wx[u] * v23[1];
        }
    }
    for (; j + 4 <= s1; j += 4) {
        int sx[4];
        float wx[4];
        unsigned pk[4];
#pragma unroll
        for (int u = 0; u < 4; ++u) sx[u] = csr_src[j + u];
#pragma unroll
        for (int u = 0; u < 4; ++u) {
            wx[u] = inv_sqrt[sx[u]];
            pk[u] = *(const unsigned*)(h1f8 + (size_t)sx[u] * NG + c4);
        }
#pragma unroll
        for (int u = 0; u < 4; ++u) {
            f32x2 v01 = __builtin_amdgcn_cvt_pk_f32_fp8(pk[u], false);
            f32x2 v23 = __builtin_amdgcn_cvt_pk_f32_fp8(pk[u], true);
            a0 += wx[u] * v01[0];
            a1 += wx[u] * v01[1];
            a2 += wx[u] * v23[0];
            a3 += wx[u] * v23[1];
        }
    }
    for (; j < s1; ++j) {
        int s = csr_src[j];
        float w = inv_sqrt[s];
        unsigned pk = *(const unsigned*)(h1f8 + (size_t)s * NG + c4);
        f32x2 v01 = __builtin_amdgcn_cvt_pk_f32_fp8(pk, false);
        f32x2 v23 = __builtin_amdgcn_cvt_pk_f32_fp8(pk, true);
        a0 += w * v01[0];
        a1 += w * v01[1];
        a2 += w * v23[0];
        a3 += w * v23[1];
    }
    float is = inv_sqrt[i], is2 = is * is;
    unsigned pks = *(const unsigned*)(h1f8 + (size_t)i * NG + c4);
    f32x2 s01 = __builtin_amdgcn_cvt_pk_f32_fp8(pks, false);
    f32x2 s23 = __builtin_amdgcn_cvt_pk_f32_fp8(pks, true);
    float4 bb = *(const float4*)(b1 + c4);
    half4 o;
    o[0] = (_Float16)fmaxf(is * a0 + s01[0] * is2 + bb.x, 0.f);
    o[1] = (_Float16)fmaxf(is * a1 + s01[1] * is2 + bb.y, 0.f);
    o[2] = (_Float16)fmaxf(is * a2 + s23[0] * is2 + bb.z, 0.f);
    o[3] = (_Float16)fmaxf(is * a3 + s23[1] * is2 + bb.w, 0.f);
    *(half4*)(x1 + (size_t)i * NG + c4) = o;
}

// ---- layer-2 agg on x1 at word positions only (W2 deferred), unroll-16 ----
__global__ __launch_bounds__(256) void agg2_kernel(const _Float16* __restrict__ x1,
                                                   const int* __restrict__ off,
                                                   const int* __restrict__ endv,
                                                   const ushort* __restrict__ csr_src,
                                                   const float* __restrict__ inv_sqrt,
                                                   const int* __restrict__ word_ids,
                                                   float* __restrict__ y) {
    int wv = threadIdx.x >> 6, lane = threadIdx.x & 63;
    int p = blockIdx.x * 4 + wv;
    if (p >= NBS) return;
    int n = word_ids[p];
    int c4 = lane * 4;
    int s0 = off[n], s1 = endv[n];
    float a0 = 0.f, a1 = 0.f, a2 = 0.f, a3 = 0.f;
    int j = s0;
    for (; j + 16 <= s1; j += 16) {
        int sx[16];
        float wx[16];
        half4 vx[16];
#pragma unroll
        for (int u = 0; u < 16; ++u) sx[u] = csr_src[j + u];
#pragma unroll
        for (int u = 0; u < 16; ++u) {
            wx[u] = inv_sqrt[sx[u]];
            vx[u] = *(const half4*)(x1 + (size_t)sx[u] * NG + c4);
        }
#pragma unroll
        for (int u = 0; u < 16; ++u) {
            a0 += wx[u] * (float)vx[u][0];
            a1 += wx[u] * (float)vx[u][1];
            a2 += wx[u] * (float)vx[u][2];
            a3 += wx[u] * (float)vx[u][3];
        }
    }
    for (; j + 4 <= s1; j += 4) {
        int sx[4];
        float wx[4];
        half4 vx[4];
#pragma unroll
        for (int u = 0; u < 4; ++u) sx[u] = csr_src[j + u];
#pragma unroll
        for (int u = 0; u < 4; ++u) {
            wx[u] = inv_sqrt[sx[u]];
            vx[u] = *(const half4*)(x1 + (size_t)sx[u] * NG + c4);
        }
#pragma unroll
        for (int u = 0; u < 4; ++u) {
            a0 += wx[u] * (float)vx[u][0];
            a1 += wx[u] * (float)vx[u][1];
            a2 += wx[u] * (float)vx[u][2];
            a3 += wx[u] * (float)vx[u][3];
        }
    }
    for (; j < s1; ++j) {
        int s = csr_src[j];
        float w = inv_sqrt[s];
        half4 hv = *(const half4*)(x1 + (size_t)s * NG + c4);
        a0 += w * (float)hv[0];
        a1 += w * (float)hv[1];
        a2 += w * (float)hv[2];
        a3 += w * (float)hv[3];
    }
    float is = inv_sqrt[n], is2 = is * is;
    half4 sv = *(const half4*)(x1 + (size_t)n * NG + c4);
    float4 o;
    o.x = is * a0 + (float)sv[0] * is2;
    o.y = is * a1 + (float)sv[1] * is2;
    o.z = is * a2 + (float)sv[2] * is2;
    o.w = is * a3 + (float)sv[3] * is2;
    *(float4*)(y + (size_t)p * NG + c4) = o;
}

extern "C" void kernel_launch(void* const* d_in, const int* in_sizes, int n_in,
                              void* d_out, int out_size, void* d_ws, size_t ws_size,
                              hipStream_t stream) {
    const float* emb = (const float*)d_in[0];       // V x D
    const float* W1  = (const float*)d_in[1];       // D x G
    const float* b1  = (const float*)d_in[2];       // G
    const float* W2  = (const float*)d_in[3];       // G x G
    const float* b2  = (const float*)d_in[4];       // G
    const int*   ei  = (const int*)d_in[5];         // 2 x E
    const int*   wid = (const int*)d_in[6];         // B x S
    float* out = (float*)d_out;

    char* w = (char*)d_ws;
    auto alloc = [&](size_t bytes) {
        void* p = (void*)w;
        w += (bytes + 255) & ~(size_t)255;
        return p;
    };
    int*    off      = (int*)alloc((size_t)NV * 4);
    int*    endv     = (int*)alloc((size_t)NV * 4);
    float*  inv_sqrt = (float*)alloc((size_t)NV * 4);
    int*    bucket_cursor = (int*)alloc((size_t)NBUCK * CPAD * 4);
    ushort* csr_src  = (ushort*)alloc((size_t)NBUCK * BCAP * 2);
    unsigned* bucket_rec = (unsigned*)alloc((size_t)NBUCK * BCAP * 4);
    ushort* W1T_h    = (ushort*)alloc((size_t)NG * NDP * 2);
    ushort* W2T_h    = (ushort*)alloc((size_t)NG * NG * 2);
    ushort* W2T_l    = (ushort*)alloc((size_t)NG * NG * 2);
    ushort* embB     = (ushort*)alloc((size_t)NV * NDP * 2);   // bf16 emb, zero-padded
    unsigned char* h1f8 = (unsigned char*)alloc((size_t)NV * NG);
    _Float16* x1     = (_Float16*)alloc((size_t)NV * NG * 2);
    float*  y        = (float*)alloc((size_t)NBS * NG * 4);

    hipMemsetAsync(bucket_cursor, 0, (size_t)NBUCK * CPAD * 4, stream);

    // prep2 (first real kernel, no upstream dep): scatter ∥ W1 ∥ W2 ∥ emb->bf16
    prep2_kernel<<<SCAT_BLOCKS + P2_W1 + P2_W2 + P2_EMB, 256, 0, stream>>>(
        ei, bucket_cursor, bucket_rec, W1, W2, W1T_h, W2T_h, W2T_l, emb, embB);
    // fused: csr_build (fixed bucket bases, no scan) ∥ gemm1 (h1 = embB@W1 -> fp8)
    csr_gemm1<<<NBUCK + GEMM1_BLOCKS, 256, 0, stream>>>(bucket_rec, bucket_cursor,
                                                        off, endv, inv_sqrt, csr_src,
                                                        embB, W1T_h, h1f8);
    // x1 = relu(norm-agg(h1) + b1)  (fp16 out)
    agg1_kernel<<<(NV + 3) / 4, 256, 0, stream>>>(h1f8, off, endv, csr_src, inv_sqrt, b1, x1);
    // y = norm-agg(x1) at word positions (fp32)
    agg2_kernel<<<(NBS + 3) / 4, 256, 0, stream>>>(x1, off, endv, csr_src, inv_sqrt, wid, y);
    // out = y @ W2 + b2  (fp32)
    {
        dim3 grid((NBS + 127) / 128, NG / 128);
        gemm_out<<<grid, 256, 0, stream>>>(y, NG, W2T_h, W2T_l, NG,
                                           NBS, NG, NG, out, b2);
    }
}